// Round 1
// baseline (743.791 us; speedup 1.0000x reference)
//
#include <hip/hip_runtime.h>
#include <math.h>

#define BB 512
#define MM 4096
#define DD 64
#define CC 256
#define EPS 1e-8f

__device__ __forceinline__ float softplusf(float x) {
    // stable softplus: log(1+exp(x))
    return (x > 20.0f) ? x : log1pf(expf(x));
}

__global__ __launch_bounds__(256) void ntm_head_kernel(
    const float* __restrict__ mem,     // (B, M, D)
    const float* __restrict__ cs,      // (B, C)
    const float* __restrict__ prev,    // (B, M)
    const float* __restrict__ Wk,      // (C, D)
    const float* __restrict__ Wb,      // (C, 1)
    const float* __restrict__ bb,      // (1,)
    const float* __restrict__ Wgate,   // (C, 1)
    const float* __restrict__ bgate,   // (1,)
    const float* __restrict__ Ws,      // (C, 3)
    const float* __restrict__ bs,      // (3,)
    const float* __restrict__ Wg,      // (C, 1)
    const float* __restrict__ bg,      // (1,)
    float* __restrict__ out)           // (B, M)
{
    __shared__ float s_cs[CC];
    __shared__ __align__(16) float s_qn[DD];
    __shared__ float s_scal[8];   // beta, gate, sk0, sk1, sk2, gamma, inv_qnorm
    __shared__ float s_logit[6];
    __shared__ float red[256];
    __shared__ float s_g[MM];     // gated weights, 16 KB

    const int tid  = threadIdx.x;
    const int b    = blockIdx.x;
    const int lane = tid & 63;
    const int wave = tid >> 6;

    s_cs[tid] = cs[b * CC + tid];
    __syncthreads();

    // ---- query partials: thread (part, d) sums c in [part*64, part*64+64) ----
    {
        const int d = tid & 63;
        const int part = tid >> 6;
        const int c0 = part * 64;
        float acc = 0.0f;
        #pragma unroll 8
        for (int c = 0; c < 64; ++c)
            acc = fmaf(s_cs[c0 + c], Wk[(c0 + c) * DD + d], acc);
        red[tid] = acc;
    }
    // ---- 6 small dot products: wave w handles logits j=2w, 2w+1 ----
    if (wave < 3) {
        const int j0 = wave * 2;
        float a0 = 0.0f, a1 = 0.0f;
        for (int c = lane; c < CC; c += 64) {
            float x = s_cs[c];
            float w0, w1;
            if (j0 == 0)      { w0 = Wb[c];       w1 = Wgate[c];    }
            else if (j0 == 2) { w0 = Ws[c * 3];   w1 = Ws[c * 3 + 1]; }
            else              { w0 = Ws[c * 3 + 2]; w1 = Wg[c];     }
            a0 = fmaf(x, w0, a0);
            a1 = fmaf(x, w1, a1);
        }
        #pragma unroll
        for (int o = 32; o > 0; o >>= 1) {
            a0 += __shfl_down(a0, o);
            a1 += __shfl_down(a1, o);
        }
        if (lane == 0) { s_logit[j0] = a0; s_logit[j0 + 1] = a1; }
    }
    __syncthreads();

    // ---- combine query partials, query norm, scalar post-processing ----
    if (tid < 64) {
        float q = red[tid] + red[64 + tid] + red[128 + tid] + red[192 + tid];
        s_qn[tid] = q;
        float n = q * q;
        #pragma unroll
        for (int o = 32; o > 0; o >>= 1) n += __shfl_down(n, o);
        if (tid == 0) {
            s_scal[6] = 1.0f / (sqrtf(n) + EPS);
            float beta = softplusf(s_logit[0] + bb[0]) + 1.0f;
            float gate = 1.0f / (1.0f + expf(-(s_logit[1] + bgate[0])));
            float l0 = s_logit[2] + bs[0];
            float l1 = s_logit[3] + bs[1];
            float l2 = s_logit[4] + bs[2];
            float mx = fmaxf(l0, fmaxf(l1, l2));
            float e0 = expf(l0 - mx), e1 = expf(l1 - mx), e2 = expf(l2 - mx);
            float inv_es = 1.0f / (e0 + e1 + e2);
            float gamma = softplusf(s_logit[5] + bg[0]) + 1.0f;
            s_scal[0] = beta; s_scal[1] = gate;
            s_scal[2] = e0 * inv_es; s_scal[3] = e1 * inv_es; s_scal[4] = e2 * inv_es;
            s_scal[5] = gamma;
        }
    }
    __syncthreads();
    if (tid < 64) s_qn[tid] *= s_scal[6];
    __syncthreads();

    const float beta = s_scal[0], gate = s_scal[1];
    const float sk0 = s_scal[2], sk1 = s_scal[3], sk2 = s_scal[4];
    const float gamma = s_scal[5];
    const float4* qn4 = (const float4*)s_qn;

    // ---- main streaming pass: cosine-sim logits for 16 m's per thread ----
    float sv[16];
    float lmax = -INFINITY;
    const float* mbase = mem + (size_t)b * MM * DD;
    for (int k = 0; k < 16; ++k) {
        const int m = tid + k * 256;
        const float4* row = (const float4*)(mbase + (size_t)m * DD);
        float dot = 0.0f, nrm = 0.0f;
        #pragma unroll
        for (int d = 0; d < 16; ++d) {
            float4 v = row[d];
            float4 q = qn4[d];
            dot = fmaf(v.x, q.x, dot); dot = fmaf(v.y, q.y, dot);
            dot = fmaf(v.z, q.z, dot); dot = fmaf(v.w, q.w, dot);
            nrm = fmaf(v.x, v.x, nrm); nrm = fmaf(v.y, v.y, nrm);
            nrm = fmaf(v.z, v.z, nrm); nrm = fmaf(v.w, v.w, nrm);
        }
        float s = beta * dot / (sqrtf(nrm) + EPS);
        sv[k] = s;
        lmax = fmaxf(lmax, s);
    }

    // ---- block-level softmax over M ----
    red[tid] = lmax; __syncthreads();
    for (int o = 128; o > 0; o >>= 1) {
        if (tid < o) red[tid] = fmaxf(red[tid], red[tid + o]);
        __syncthreads();
    }
    const float mx = red[0];
    __syncthreads();
    float lsum = 0.0f;
    for (int k = 0; k < 16; ++k) { float e = expf(sv[k] - mx); sv[k] = e; lsum += e; }
    red[tid] = lsum; __syncthreads();
    for (int o = 128; o > 0; o >>= 1) {
        if (tid < o) red[tid] += red[tid + o];
        __syncthreads();
    }
    const float inv_sum = 1.0f / red[0];
    __syncthreads();

    // ---- gate interpolation; stage gated weights in LDS ----
    const float* prow = prev + (size_t)b * MM;
    for (int k = 0; k < 16; ++k) {
        const int m = tid + k * 256;
        float cw = sv[k] * inv_sum;
        s_g[m] = gate * cw + (1.0f - gate) * prow[m];
    }
    __syncthreads();

    // ---- circular 3-tap shift + sharpening ----
    float psum = 0.0f;
    for (int k = 0; k < 16; ++k) {
        const int m = tid + k * 256;
        const int ml = (m == 0) ? (MM - 1) : (m - 1);
        const int mr = (m == MM - 1) ? 0 : (m + 1);
        // shifted[j] = g[(j-1)%M]*sk0 + g[j]*sk1 + g[(j+1)%M]*sk2
        float sh = s_g[ml] * sk0 + s_g[m] * sk1 + s_g[mr] * sk2;
        float p = powf(sh + EPS, gamma);
        sv[k] = p;
        psum += p;
    }
    red[tid] = psum; __syncthreads();
    for (int o = 128; o > 0; o >>= 1) {
        if (tid < o) red[tid] += red[tid + o];
        __syncthreads();
    }
    const float inv_total = 1.0f / (red[0] + EPS);

    float* orow = out + (size_t)b * MM;
    for (int k = 0; k < 16; ++k) {
        const int m = tid + k * 256;
        orow[m] = sv[k] * inv_total;
    }
}

extern "C" void kernel_launch(void* const* d_in, const int* in_sizes, int n_in,
                              void* d_out, int out_size, void* d_ws, size_t ws_size,
                              hipStream_t stream) {
    ntm_head_kernel<<<dim3(BB), dim3(256), 0, stream>>>(
        (const float*)d_in[0],  // memory
        (const float*)d_in[1],  // controller_state
        (const float*)d_in[2],  // previous_weights
        (const float*)d_in[3],  // Wk
        (const float*)d_in[4],  // Wb
        (const float*)d_in[5],  // bb
        (const float*)d_in[6],  // Wgate
        (const float*)d_in[7],  // bgate
        (const float*)d_in[8],  // Ws
        (const float*)d_in[9],  // bs
        (const float*)d_in[10], // Wg
        (const float*)d_in[11], // bg
        (float*)d_out);
}

// Round 2
// 727.629 us; speedup vs baseline: 1.0222x; 1.0222x over previous
//
#include <hip/hip_runtime.h>
#include <math.h>

#define BB 512
#define MM 4096
#define DD 64
#define CC 256
#define THREADS 512
#define EPS 1e-8f

__device__ __forceinline__ float softplusf(float x) {
    return (x > 20.0f) ? x : log1pf(expf(x));
}

__global__ __launch_bounds__(THREADS) void ntm_head_kernel(
    const float* __restrict__ mem,     // (B, M, D)
    const float* __restrict__ cs,      // (B, C)
    const float* __restrict__ prev,    // (B, M)
    const float* __restrict__ Wk,      // (C, D)
    const float* __restrict__ Wb,      // (C, 1)
    const float* __restrict__ bb,      // (1,)
    const float* __restrict__ Wgate,   // (C, 1)
    const float* __restrict__ bgate,   // (1,)
    const float* __restrict__ Ws,      // (C, 3)
    const float* __restrict__ bs,      // (3,)
    const float* __restrict__ Wg,      // (C, 1)
    const float* __restrict__ bg,      // (1,)
    float* __restrict__ out)           // (B, M)
{
    __shared__ float s_cs[CC];
    __shared__ __align__(16) float s_qn[DD];
    __shared__ float s_scal[8];   // beta, gate, sk0, sk1, sk2, gamma, inv_qnorm
    __shared__ float s_logit[6];
    __shared__ float red[THREADS];
    __shared__ float s_w[MM];     // sim -> gated (in place), 16 KB

    const int tid  = threadIdx.x;
    const int b    = blockIdx.x;
    const int lane = tid & 63;
    const int wave = tid >> 6;    // 0..7

    if (tid < CC) s_cs[tid] = cs[b * CC + tid];
    __syncthreads();

    // ---- query partials: threads 0..255, thread (part, d) sums 64 c's ----
    if (tid < 256) {
        const int d = tid & 63;
        const int part = tid >> 6;
        const int c0 = part * 64;
        float acc = 0.0f;
        #pragma unroll 8
        for (int c = 0; c < 64; ++c)
            acc = fmaf(s_cs[c0 + c], Wk[(c0 + c) * DD + d], acc);
        red[tid] = acc;
    }
    // ---- 6 small dot products: wave w handles logits j=2w, 2w+1 ----
    if (wave < 3) {
        const int j0 = wave * 2;
        float a0 = 0.0f, a1 = 0.0f;
        for (int c = lane; c < CC; c += 64) {
            float x = s_cs[c];
            float w0, w1;
            if (j0 == 0)      { w0 = Wb[c];         w1 = Wgate[c];      }
            else if (j0 == 2) { w0 = Ws[c * 3];     w1 = Ws[c * 3 + 1]; }
            else              { w0 = Ws[c * 3 + 2]; w1 = Wg[c];         }
            a0 = fmaf(x, w0, a0);
            a1 = fmaf(x, w1, a1);
        }
        #pragma unroll
        for (int o = 32; o > 0; o >>= 1) {
            a0 += __shfl_down(a0, o);
            a1 += __shfl_down(a1, o);
        }
        if (lane == 0) { s_logit[j0] = a0; s_logit[j0 + 1] = a1; }
    }
    __syncthreads();

    // ---- combine query partials, norm, scalar post-processing ----
    if (tid < 64) {
        float q = red[tid] + red[64 + tid] + red[128 + tid] + red[192 + tid];
        s_qn[tid] = q;
        float n = q * q;
        #pragma unroll
        for (int o = 32; o > 0; o >>= 1) n += __shfl_down(n, o);
        if (tid == 0) {
            s_scal[6] = 1.0f / (sqrtf(n) + EPS);
            float beta = softplusf(s_logit[0] + bb[0]) + 1.0f;
            float gate = 1.0f / (1.0f + expf(-(s_logit[1] + bgate[0])));
            float l0 = s_logit[2] + bs[0];
            float l1 = s_logit[3] + bs[1];
            float l2 = s_logit[4] + bs[2];
            float mx = fmaxf(l0, fmaxf(l1, l2));
            float e0 = expf(l0 - mx), e1 = expf(l1 - mx), e2 = expf(l2 - mx);
            float inv_es = 1.0f / (e0 + e1 + e2);
            float gamma = softplusf(s_logit[5] + bg[0]) + 1.0f;
            s_scal[0] = beta; s_scal[1] = gate;
            s_scal[2] = e0 * inv_es; s_scal[3] = e1 * inv_es; s_scal[4] = e2 * inv_es;
            s_scal[5] = gamma;
        }
    }
    __syncthreads();
    if (tid < 64) s_qn[tid] *= s_scal[6];
    __syncthreads();

    const float beta = s_scal[0], gate = s_scal[1];
    const float sk0 = s_scal[2], sk1 = s_scal[3], sk2 = s_scal[4];
    const float gamma = s_scal[5];

    // ---- main streaming pass: lane-cooperative, fully coalesced ----
    // 16 lanes per row (sub = float4 index), 4 rows per wave-iteration.
    // Wave w owns rows [w*512, w*512+512) -> 128 iterations of 1 KB loads.
    {
        const int sub = lane & 15;
        const int r   = lane >> 4;
        const float4 q4 = ((const float4*)s_qn)[sub];
        const float* mbase = mem + (size_t)b * MM * DD;
        const int m0 = wave * 512 + r;
        #pragma unroll 4
        for (int t = 0; t < 128; ++t) {
            const int m = m0 + t * 4;
            const float4 v = *(const float4*)(mbase + (size_t)m * DD + sub * 4);
            float dot = v.x * q4.x;
            dot = fmaf(v.y, q4.y, dot);
            dot = fmaf(v.z, q4.z, dot);
            dot = fmaf(v.w, q4.w, dot);
            float nrm = v.x * v.x;
            nrm = fmaf(v.y, v.y, nrm);
            nrm = fmaf(v.z, v.z, nrm);
            nrm = fmaf(v.w, v.w, nrm);
            #pragma unroll
            for (int msk = 1; msk < 16; msk <<= 1) {
                dot += __shfl_xor(dot, msk);
                nrm += __shfl_xor(nrm, msk);
            }
            if (sub == 0)
                s_w[m] = beta * dot / (sqrtf(nrm) + EPS);
        }
    }
    __syncthreads();

    // ---- block softmax over M, then gate interpolation (in-place) ----
    float v[8];
    float lmax = -INFINITY;
    #pragma unroll
    for (int k = 0; k < 8; ++k) {
        v[k] = s_w[tid + k * THREADS];
        lmax = fmaxf(lmax, v[k]);
    }
    red[tid] = lmax; __syncthreads();
    for (int o = THREADS / 2; o > 0; o >>= 1) {
        if (tid < o) red[tid] = fmaxf(red[tid], red[tid + o]);
        __syncthreads();
    }
    const float mx = red[0];
    __syncthreads();
    float lsum = 0.0f;
    #pragma unroll
    for (int k = 0; k < 8; ++k) { float e = expf(v[k] - mx); v[k] = e; lsum += e; }
    red[tid] = lsum; __syncthreads();
    for (int o = THREADS / 2; o > 0; o >>= 1) {
        if (tid < o) red[tid] += red[tid + o];
        __syncthreads();
    }
    const float inv_sum = 1.0f / red[0];
    __syncthreads();

    const float* prow = prev + (size_t)b * MM;
    #pragma unroll
    for (int k = 0; k < 8; ++k) {
        const int m = tid + k * THREADS;
        s_w[m] = gate * (v[k] * inv_sum) + (1.0f - gate) * prow[m];
    }
    __syncthreads();

    // ---- circular 3-tap shift + sharpening ----
    float psum = 0.0f;
    #pragma unroll
    for (int k = 0; k < 8; ++k) {
        const int m = tid + k * THREADS;
        const int ml = (m == 0) ? (MM - 1) : (m - 1);
        const int mr = (m == MM - 1) ? 0 : (m + 1);
        float sh = s_w[ml] * sk0 + s_w[m] * sk1 + s_w[mr] * sk2;
        float p = powf(sh + EPS, gamma);
        v[k] = p;
        psum += p;
    }
    red[tid] = psum; __syncthreads();
    for (int o = THREADS / 2; o > 0; o >>= 1) {
        if (tid < o) red[tid] += red[tid + o];
        __syncthreads();
    }
    const float inv_total = 1.0f / (red[0] + EPS);

    float* orow = out + (size_t)b * MM;
    #pragma unroll
    for (int k = 0; k < 8; ++k) {
        const int m = tid + k * THREADS;
        orow[m] = v[k] * inv_total;
    }
}

extern "C" void kernel_launch(void* const* d_in, const int* in_sizes, int n_in,
                              void* d_out, int out_size, void* d_ws, size_t ws_size,
                              hipStream_t stream) {
    ntm_head_kernel<<<dim3(BB), dim3(THREADS), 0, stream>>>(
        (const float*)d_in[0],  // memory
        (const float*)d_in[1],  // controller_state
        (const float*)d_in[2],  // previous_weights
        (const float*)d_in[3],  // Wk
        (const float*)d_in[4],  // Wb
        (const float*)d_in[5],  // bb
        (const float*)d_in[6],  // Wgate
        (const float*)d_in[7],  // bgate
        (const float*)d_in[8],  // Ws
        (const float*)d_in[9],  // bs
        (const float*)d_in[10], // Wg
        (const float*)d_in[11], // bg
        (float*)d_out);
}